// Round 1
// 194.208 us; speedup vs baseline: 1.1157x; 1.1157x over previous
//
#include <hip/hip_runtime.h>
#include <math.h>

#define DT 0.1f

typedef __attribute__((ext_vector_type(4)))  short short4v;
typedef __attribute__((ext_vector_type(8)))  short short8;
typedef __attribute__((ext_vector_type(16))) float f32x16;

__device__ __forceinline__ short f2bf(float x) {
    unsigned int u = __float_as_uint(x);
    unsigned int r = (u + 0x7fffu + ((u >> 16) & 1u)) >> 16;  // RNE
    return (short)r;
}
__device__ __forceinline__ float bf2f(short s) {
    return __uint_as_float(((unsigned int)(unsigned short)s) << 16);
}
__device__ __forceinline__ float tanh_fast(float x) {
    float e = __expf(x + x);
    float r = __builtin_amdgcn_rcpf(e + 1.f);
    return __builtin_fmaf(-2.f, r, 1.f);
}

// ---------------- weight packing: 32x32x16 MFMA B-fragment order -----------
// lane holds B[k = kt*16 + (lane>>5)*8 + j][n = nt*32 + (lane&31)]
// at out[((nt*KT + kt)*64 + lane)*8 + j],  KT = K/16   (verified R5)
__device__ __forceinline__ void pack32_body(const float* __restrict__ W,
                                            short* __restrict__ out,
                                            int K, int N, int idx, bool trans)
{
    int j = idx & 7, lane = (idx >> 3) & 63, rest = idx >> 9;
    int KT = K >> 4;
    int kt = rest % KT, nt = rest / KT;
    int k = kt * 16 + (lane >> 5) * 8 + j;
    int n = nt * 32 + (lane & 31);
    out[idx] = f2bf(trans ? W[n * K + k] : W[k * N + n]);
}

// One launch for ALL preprocessing:
//   blocks [   0, 512): S = f(W1^T W1) computed AND written in packed layout
//   blocks [ 512, 768): W2      -> PB2   (K=256,N=256, direct)
//   blocks [ 768,1024): W2      -> PB2T  (K=256,N=256, trans)
//   blocks [1024,1536): W1      -> PB1q  (K=512,N=256, direct)
//   blocks [1536,2048): W1[512:]-> PB1Tp (K=256,N=512, trans)
//   blocks [2048,2560): z       -> zpA   (A-frag pack via LDS)
__global__ __launch_bounds__(256)
void prep(const float* __restrict__ W1, const float* __restrict__ W2,
          const float* __restrict__ z,
          short* __restrict__ PBSq, short* __restrict__ PBSp,
          short* __restrict__ PB2, short* __restrict__ PB2T,
          short* __restrict__ PB1q, short* __restrict__ PB1Tp,
          short* __restrict__ zpA)
{
    __shared__ short zb[32 * 520];
    const int tid = threadIdx.x;
    const int b = blockIdx.x;

    if (b < 512) {
        // S_qp = -0.5*dt * W1^T[:, :512] @ W1[512:, :]   (b <  256, k = b)
        // S_pq =      dt * W1^T[:, 512:] @ W1[:512, :]   (b >= 256, k = b-256)
        const int n = tid;
        float s0 = 0.f, s1 = 0.f, s2 = 0.f, s3 = 0.f;
        int k; float coef; short* dst;
        if (b < 256) {
            k = b; coef = -0.5f * DT; dst = PBSq;
            for (int c = 0; c < 512; c += 4) {
                s0 = __builtin_fmaf(W1[(c + 0) * 256 + k], W1[(512 + c + 0) * 256 + n], s0);
                s1 = __builtin_fmaf(W1[(c + 1) * 256 + k], W1[(512 + c + 1) * 256 + n], s1);
                s2 = __builtin_fmaf(W1[(c + 2) * 256 + k], W1[(512 + c + 2) * 256 + n], s2);
                s3 = __builtin_fmaf(W1[(c + 3) * 256 + k], W1[(512 + c + 3) * 256 + n], s3);
            }
        } else {
            k = b - 256; coef = DT; dst = PBSp;
            for (int c = 0; c < 512; c += 4) {
                s0 = __builtin_fmaf(W1[(512 + c + 0) * 256 + k], W1[(c + 0) * 256 + n], s0);
                s1 = __builtin_fmaf(W1[(512 + c + 1) * 256 + k], W1[(c + 1) * 256 + n], s1);
                s2 = __builtin_fmaf(W1[(512 + c + 2) * 256 + k], W1[(c + 2) * 256 + n], s2);
                s3 = __builtin_fmaf(W1[(512 + c + 3) * 256 + k], W1[(c + 3) * 256 + n], s3);
            }
        }
        float v = coef * ((s0 + s1) + (s2 + s3));
        // write directly at packed B-frag position (inverse of pack32_direct)
        int kt = k >> 4, r = k & 15;
        int lane = (r >> 3) * 32 + (n & 31), nt = n >> 5;
        dst[(((nt * 16 + kt) * 64 + lane) << 3) + (r & 7)] = f2bf(v);
    } else if (b < 768) {
        pack32_body(W2, PB2, 256, 256, (b - 512) * 256 + tid, false);
    } else if (b < 1024) {
        pack32_body(W2, PB2T, 256, 256, (b - 768) * 256 + tid, true);
    } else if (b < 1536) {
        pack32_body(W1, PB1q, 512, 256, (b - 1024) * 256 + tid, false);
    } else if (b < 2048) {
        pack32_body(W1 + 512 * 256, PB1Tp, 256, 512, (b - 1536) * 256 + tid, true);
    } else {
        // z (16384x512 fp32) -> A-frag-packed bf16, coalesced via LDS staging.
        const int bx = b - 2048;               // 512 blocks x 32 rows
#pragma unroll
        for (int j = 0; j < 16; ++j) {
            int lin = j * 256 + tid;           // 4096 float4
            int r = lin >> 7, c4 = lin & 127;
            float4 v = ((const float4*)z)[(size_t)(bx * 32 + r) * 128 + c4];
            short4v pk;
            pk.x = f2bf(v.x); pk.y = f2bf(v.y); pk.z = f2bf(v.z); pk.w = f2bf(v.w);
            *(short4v*)&zb[r * 520 + c4 * 4] = pk;
        }
        __syncthreads();
        const int lane = tid & 63, w = tid >> 6;
        const int m = lane & 31, lh = lane >> 5;
#pragma unroll
        for (int j = 0; j < 8; ++j) {
            int kt = w * 8 + j;
            short8 f = *(const short8*)&zb[m * 520 + kt * 16 + lh * 8];
            *(short8*)(zpA + (((size_t)bx * 32 + kt) * 64 + lane) * 8) = f;
        }
    }
}

// ---------------- LDS tile layout (C-layout-native, rotation swizzle) ------
// (verified R5) tile (nt,mt2): 64 slots x 16 shorts; rot = ((l31>>2)&3)*4
__device__ __forceinline__ short8 lds_frag(const short* Ac, int kt, int mt2,
                                           int l31, int lh, int rot)
{
    int nt_s = kt >> 1;
    int po = (((kt & 1) * 2 + lh) * 4 + rot) & 15;
    int base = ((nt_s * 2 + mt2) * 64 + l31) * 16 + po;
    short4v x = *(const short4v*)&Ac[base];
    short4v y = *(const short4v*)&Ac[base + 512];
    short8 r;
    r[0] = x.x; r[1] = x.y; r[2] = x.z; r[3] = x.w;
    r[4] = y.x; r[5] = y.y; r[6] = y.z; r[7] = y.w;
    return r;
}
__device__ __forceinline__ void store_tile(short* Ac, int nt, int mt2, int lane,
                                           int rot, const f32x16 v)
{
    int base = ((nt * 2 + mt2) * 64 + lane) * 16;
#pragma unroll
    for (int c = 0; c < 4; ++c) {
        short4v pk;
        pk.x = f2bf(v[4 * c + 0]); pk.y = f2bf(v[4 * c + 1]);
        pk.z = f2bf(v[4 * c + 2]); pk.w = f2bf(v[4 * c + 3]);
        *(short4v*)&Ac[base + ((4 * c + rot) & 15)] = pk;
    }
}

// K=256 gemm: A (both mt tiles) from LDS, B (this wave's nt strip) from L2.
__device__ __forceinline__ void gemm_nt(const short* Ac, int l31, int lh, int rot,
                                        const short8* __restrict__ Bf,
                                        f32x16& acc0, f32x16& acc1)
{
    short8 pb[4];
#pragma unroll
    for (int k = 0; k < 4; ++k) pb[k] = Bf[k * 64];
    short8 pa0 = lds_frag(Ac, 0, 0, l31, lh, rot);
    short8 pa1 = lds_frag(Ac, 0, 1, l31, lh, rot);
#pragma unroll
    for (int kt = 0; kt < 16; ++kt) {
        short8 ca0 = pa0, ca1 = pa1, cb = pb[kt & 3];
        if (kt + 4 < 16) pb[kt & 3] = Bf[(kt + 4) * 64];
        if (kt + 1 < 16) {
            pa0 = lds_frag(Ac, kt + 1, 0, l31, lh, rot);
            pa1 = lds_frag(Ac, kt + 1, 1, l31, lh, rot);
        }
        acc0 = __builtin_amdgcn_mfma_f32_32x32x16_bf16(ca0, cb, acc0, 0, 0, 0);
        acc1 = __builtin_amdgcn_mfma_f32_32x32x16_bf16(ca1, cb, acc1, 0, 0, 0);
    }
}

// ---------------- fused leapfrog: 1 block/CU, wave = 64 rows x 32 cols -----
// Now also contains the final out-gemm (dsum @ W1^T[:,512:]) as an epilogue:
// dsum frags stay in LDS, no global round-trip, no extra launch.
__global__ __launch_bounds__(512, 2)
void mega(const short* __restrict__ zpA,
          const short* __restrict__ PB1q,
          const short* __restrict__ PB2,
          const short* __restrict__ PB2T,
          const short* __restrict__ PBSq,
          const short* __restrict__ PBSp,
          const float* __restrict__ b1,
          const float* __restrict__ b2,
          const float* __restrict__ W3,
          const short* __restrict__ PB1Tp,
          const float* __restrict__ z,
          float* __restrict__ out)
{
    __shared__ alignas(16) short smem[32768];   // 64 KB
    short* h1_c = smem;             // 8 nt x 2 mt x 64 x 16
    short* da_c = smem + 16384;

    const int tid = threadIdx.x;
    const int lane = tid & 63, w = tid >> 6;   // w = nt strip, 0..7
    const int l31 = lane & 31, lh = lane >> 5;
    const int rot = ((l31 >> 2) & 3) * 4;
    const int bx = blockIdx.x;

    const int col = w * 32 + l31;
    const float b1v = b1[col], b2v = b2[col], w3v = W3[col];

    f32x16 A1[2];  A1[0] = 0.f; A1[1] = 0.f;
    f32x16 dsum[2]; dsum[0] = 0.f; dsum[1] = 0.f;

    // GEMM1: A1 = z @ W1[:512,:]  (K=512, A frags from global, KT=32)
    {
        const short8* Af0 = (const short8*)zpA + ((size_t)(bx * 2 + 0) * 32) * 64 + lane;
        const short8* Af1 = (const short8*)zpA + ((size_t)(bx * 2 + 1) * 32) * 64 + lane;
        const short8* Bf  = (const short8*)PB1q + ((size_t)w * 32) * 64 + lane;
        short8 pa0[2], pa1[2], pb[4];
#pragma unroll
        for (int k = 0; k < 2; ++k) { pa0[k] = Af0[k * 64]; pa1[k] = Af1[k * 64]; }
#pragma unroll
        for (int k = 0; k < 4; ++k) pb[k] = Bf[k * 64];
#pragma unroll
        for (int kt = 0; kt < 32; ++kt) {
            short8 ca0 = pa0[kt & 1], ca1 = pa1[kt & 1], cb = pb[kt & 3];
            if (kt + 2 < 32) {
                pa0[kt & 1] = Af0[(kt + 2) * 64];
                pa1[kt & 1] = Af1[(kt + 2) * 64];
            }
            if (kt + 4 < 32) pb[kt & 3] = Bf[(kt + 4) * 64];
            A1[0] = __builtin_amdgcn_mfma_f32_32x32x16_bf16(ca0, cb, A1[0], 0, 0, 0);
            A1[1] = __builtin_amdgcn_mfma_f32_32x32x16_bf16(ca1, cb, A1[1], 0, 0, 0);
        }
    }

    for (int it = 0; it < 8; ++it) {
        const bool isq = ((it % 3) == 1);

        // P1: h1 = tanh(A1 + b1)
#pragma unroll
        for (int t = 0; t < 2; ++t) {
            f32x16 hv;
#pragma unroll
            for (int r = 0; r < 16; ++r) hv[r] = tanh_fast(A1[t][r] + b1v);
            store_tile(h1_c, w, t, lane, rot, hv);
        }
        __syncthreads();

        // P2: da2 = W3*(1-tanh^2(h1@W2 + b2))
        {
            f32x16 t0 = 0.f, t1 = 0.f;
            gemm_nt(h1_c, l31, lh, rot, (const short8*)PB2 + ((size_t)w * 16) * 64 + lane, t0, t1);
#pragma unroll
            for (int t = 0; t < 2; ++t) {
                f32x16& tt = t ? t1 : t0;
                f32x16 d;
#pragma unroll
                for (int r = 0; r < 16; ++r) {
                    float ta = tanh_fast(tt[r] + b2v);
                    d[r] = w3v * (1.f - ta * ta);
                }
                store_tile(da_c, w, t, lane, rot, d);
            }
        }
        __syncthreads();

        // P3: da1 = (da2@W2^T) * (1-h1^2)
        {
            f32x16 t0 = 0.f, t1 = 0.f;
            gemm_nt(da_c, l31, lh, rot, (const short8*)PB2T + ((size_t)w * 16) * 64 + lane, t0, t1);
            __syncthreads();   // all waves done reading da2
#pragma unroll
            for (int t = 0; t < 2; ++t) {
                f32x16& tt = t ? t1 : t0;
                f32x16 d;
                const int basei = ((w * 2 + t) * 64 + lane) * 16;
#pragma unroll
                for (int c = 0; c < 4; ++c) {
                    short4v h4 = *(const short4v*)&h1_c[basei + ((4 * c + rot) & 15)];
                    float h0 = bf2f(h4.x), h1f = bf2f(h4.y);
                    float h2 = bf2f(h4.z), h3 = bf2f(h4.w);
                    d[4 * c + 0] = tt[4 * c + 0] * (1.f - h0 * h0);
                    d[4 * c + 1] = tt[4 * c + 1] * (1.f - h1f * h1f);
                    d[4 * c + 2] = tt[4 * c + 2] * (1.f - h2 * h2);
                    d[4 * c + 3] = tt[4 * c + 3] * (1.f - h3 * h3);
                }
                if (isq) dsum[t] += d;
                store_tile(da_c, w, t, lane, rot, d);
            }
        }
        __syncthreads();

        // P4: A1 += da1 @ S  (coef folded into S; skip on last eval)
        if (it < 7) {
            const short* S = isq ? PBSp : PBSq;
            gemm_nt(da_c, l31, lh, rot, (const short8*)S + ((size_t)w * 16) * 64 + lane,
                    A1[0], A1[1]);
            // safe: every wave's P4 reads complete before it reaches the
            // next-iteration P1 barrier, which precedes any da_c overwrite.
        }
    }

    // ---- fused out-gemm: C = dsum @ W1^T[:,512:], out = z + DT*C ----------
    store_tile(da_c, w, 0, lane, rot, dsum[0]);
    store_tile(da_c, w, 1, lane, rot, dsum[1]);
    __syncthreads();

    const int mt2 = w >> 2, nq = w & 3;       // row-group / col-quarter
    f32x16 acc[4];
#pragma unroll
    for (int t = 0; t < 4; ++t) acc[t] = 0.f;
    const short8* Bf[4];
#pragma unroll
    for (int t = 0; t < 4; ++t)
        Bf[t] = (const short8*)PB1Tp + (size_t)(nq * 4 + t) * 16 * 64 + lane;

    short8 br[2][4];
#pragma unroll
    for (int k = 0; k < 2; ++k)
#pragma unroll
        for (int t = 0; t < 4; ++t) br[k][t] = Bf[t][k * 64];
#pragma unroll
    for (int kt = 0; kt < 16; ++kt) {
        short8 a = lds_frag(da_c, kt, mt2, l31, lh, rot);
        short8 bb[4];
#pragma unroll
        for (int t = 0; t < 4; ++t) bb[t] = br[kt & 1][t];
        if (kt + 2 < 16) {
#pragma unroll
            for (int t = 0; t < 4; ++t) br[kt & 1][t] = Bf[t][(kt + 2) * 64];
        }
#pragma unroll
        for (int t = 0; t < 4; ++t)
            acc[t] = __builtin_amdgcn_mfma_f32_32x32x16_bf16(a, bb[t], acc[t], 0, 0, 0);
    }
    __syncthreads();   // all A-frag reads of da_c done before Ct overwrite

    // coalesced epilogue via LDS fp32 (reuses the 64 KB), two 32-row passes
    float* Ct = (float*)smem;                 // 32 x 512 fp32
#pragma unroll
    for (int p = 0; p < 2; ++p) {
        if (mt2 == p) {
#pragma unroll
            for (int t = 0; t < 4; ++t) {
                const int c = (nq * 4 + t) * 32 + l31;
#pragma unroll
                for (int r = 0; r < 16; ++r) {
                    int row = (r & 3) + 8 * (r >> 2) + 4 * lh;
                    Ct[row * 512 + c] = acc[t][r];
                }
            }
        }
        __syncthreads();
#pragma unroll
        for (int j = 0; j < 8; ++j) {
            int lin = j * 512 + tid;          // 4096 float4
            int r = lin >> 7, c4 = lin & 127;
            size_t gi = (size_t)(bx * 64 + p * 32 + r) * 128 + c4;
            float4 zv = ((const float4*)z)[gi];
            float4 cv = *(const float4*)&Ct[r * 512 + c4 * 4];
            float4 ov;
            ov.x = zv.x + DT * cv.x; ov.y = zv.y + DT * cv.y;
            ov.z = zv.z + DT * cv.z; ov.w = zv.w + DT * cv.w;
            ((float4*)out)[gi] = ov;
        }
        __syncthreads();
    }
}

extern "C" void kernel_launch(void* const* d_in, const int* in_sizes, int n_in,
                              void* d_out, int out_size, void* d_ws, size_t ws_size,
                              hipStream_t stream)
{
    const float* z  = (const float*)d_in[0];
    const float* W1 = (const float*)d_in[1];   // 1024 x 256
    const float* b1 = (const float*)d_in[2];
    const float* W2 = (const float*)d_in[3];   // 256 x 256
    const float* b2 = (const float*)d_in[4];
    const float* W3 = (const float*)d_in[5];   // 256 x 1
    float* out = (float*)d_out;

    short* PB2   = (short*)d_ws;
    short* PB2T  = PB2   + 65536;
    short* PBSq  = PB2T  + 65536;
    short* PBSp  = PBSq  + 65536;
    short* PB1q  = PBSp  + 65536;              // K=512,N=256
    short* PB1Tp = PB1q  + 131072;             // K=256,N=512
    short* zpA   = PB1Tp + 131072;             // 16 MB

    prep<<<2560, 256, 0, stream>>>(W1, W2, z, PBSq, PBSp, PB2, PB2T,
                                   PB1q, PB1Tp, zpA);
    mega<<<256, 512, 0, stream>>>(zpA, PB1q, PB2, PB2T, PBSq, PBSp,
                                  b1, b2, W3, PB1Tp, z, out);
}